// Round 3
// baseline (54.298 us; speedup 1.0000x reference)
//
#include <hip/hip_runtime.h>
#include <math.h>

#define NB 256
#define ND 2048
#define T_K 10.0f
#define SCAN_BLOCKS 2048

// ---------------------------------------------------------------------------
// Kernel 1: per-row mean & std (ddof=1), fused minbits init.
// One block (256 threads) per row; 2 float4 per thread.
// ---------------------------------------------------------------------------
__global__ __launch_bounds__(256) void stats_kernel(const float* __restrict__ feat,
                                                    float* __restrict__ stats,
                                                    unsigned int* __restrict__ minbits) {
    const int b   = blockIdx.x;
    const int tid = threadIdx.x;
    if (tid == 0) minbits[b] = 0x7F800000u;  // +inf (fused init)

    const float4* row = (const float4*)(feat + (size_t)b * ND);
    float sum = 0.f, sumsq = 0.f;
#pragma unroll
    for (int i = 0; i < 2; ++i) {
        float4 v = row[tid + i * 256];
        sum   += v.x + v.y + v.z + v.w;
        sumsq += v.x * v.x + v.y * v.y + v.z * v.z + v.w * v.w;
    }
#pragma unroll
    for (int off = 32; off > 0; off >>= 1) {
        sum   += __shfl_down(sum, off, 64);
        sumsq += __shfl_down(sumsq, off, 64);
    }
    __shared__ float ls[4], lq[4];
    const int lane = tid & 63, wid = tid >> 6;
    if (lane == 0) { ls[wid] = sum; lq[wid] = sumsq; }
    __syncthreads();
    if (tid == 0) {
        float S  = ls[0] + ls[1] + ls[2] + ls[3];
        float Q2 = lq[0] + lq[1] + lq[2] + lq[3];
        float mean = S / (float)ND;
        float var  = (Q2 - S * mean) / (float)(ND - 1);
        var = fmaxf(var, 0.f);
        stats[b]      = mean;
        stats[NB + b] = sqrtf(var);
    }
}

// ---------------------------------------------------------------------------
// Kernel 2: brute-force min scan. Algebraic form:
//   d = (m-mu)^2 + (s-sg)^2 = c_k + [ -2m*mu - 2s*sg + (mu^2+sg^2) ]
// Track min of the bracketed d' (3 VALU ops/pair), add c_k at the end.
// Lane l owns samples b = l+64k (k=0..3); 16 independent fmin chains.
// Wave-uniform scalar loads (readfirstlane), 4-quad unroll (16 pts/iter).
// ---------------------------------------------------------------------------
__global__ __launch_bounds__(256) void scan_kernel(const float* __restrict__ mus,
                                                   const float* __restrict__ sigmas,
                                                   const float* __restrict__ stats,
                                                   unsigned int* __restrict__ minbits,
                                                   int Q) {
    const int lane = threadIdx.x & 63;
    const int wid  = threadIdx.x >> 6;

    float m2[4], s2[4];
#pragma unroll
    for (int k = 0; k < 4; ++k) {
        m2[k] = -2.f * stats[lane + 64 * k];
        s2[k] = -2.f * stats[NB + lane + 64 * k];
    }

    float acc[4][4];
#pragma unroll
    for (int k = 0; k < 4; ++k)
#pragma unroll
        for (int e = 0; e < 4; ++e) acc[k][e] = INFINITY;

    const int nquad = Q >> 2;
    const int gw    = blockIdx.x * 4 + wid;
    const int nw    = SCAN_BLOCKS * 4;
    const int chunk = (nquad + nw - 1) / nw;
    const int start = gw * chunk;
    const int end   = min(start + chunk, nquad);

    const float4* mu4 = (const float4*)mus;
    const float4* sg4 = (const float4*)sigmas;

    int iq = start;
    for (; iq + 4 <= end; iq += 4) {
        const int iqu = __builtin_amdgcn_readfirstlane(iq);
        float4 mu[4], sg[4];
#pragma unroll
        for (int j = 0; j < 4; ++j) { mu[j] = mu4[iqu + j]; sg[j] = sg4[iqu + j]; }
#pragma unroll
        for (int j = 0; j < 4; ++j) {
            const float r0 = fmaf(mu[j].x, mu[j].x, sg[j].x * sg[j].x);
            const float r1 = fmaf(mu[j].y, mu[j].y, sg[j].y * sg[j].y);
            const float r2 = fmaf(mu[j].z, mu[j].z, sg[j].z * sg[j].z);
            const float r3 = fmaf(mu[j].w, mu[j].w, sg[j].w * sg[j].w);
#pragma unroll
            for (int k = 0; k < 4; ++k) {
                acc[k][0] = fminf(acc[k][0], fmaf(m2[k], mu[j].x, fmaf(s2[k], sg[j].x, r0)));
                acc[k][1] = fminf(acc[k][1], fmaf(m2[k], mu[j].y, fmaf(s2[k], sg[j].y, r1)));
                acc[k][2] = fminf(acc[k][2], fmaf(m2[k], mu[j].z, fmaf(s2[k], sg[j].z, r2)));
                acc[k][3] = fminf(acc[k][3], fmaf(m2[k], mu[j].w, fmaf(s2[k], sg[j].w, r3)));
            }
        }
    }
    for (; iq < end; ++iq) {  // quad singles tail
        const int iqu = __builtin_amdgcn_readfirstlane(iq);
        float4 mu = mu4[iqu], sg = sg4[iqu];
        const float r0 = fmaf(mu.x, mu.x, sg.x * sg.x);
        const float r1 = fmaf(mu.y, mu.y, sg.y * sg.y);
        const float r2 = fmaf(mu.z, mu.z, sg.z * sg.z);
        const float r3 = fmaf(mu.w, mu.w, sg.w * sg.w);
#pragma unroll
        for (int k = 0; k < 4; ++k) {
            acc[k][0] = fminf(acc[k][0], fmaf(m2[k], mu.x, fmaf(s2[k], sg.x, r0)));
            acc[k][1] = fminf(acc[k][1], fmaf(m2[k], mu.y, fmaf(s2[k], sg.y, r1)));
            acc[k][2] = fminf(acc[k][2], fmaf(m2[k], mu.z, fmaf(s2[k], sg.z, r2)));
            acc[k][3] = fminf(acc[k][3], fmaf(m2[k], mu.w, fmaf(s2[k], sg.w, r3)));
        }
    }
    // element tail (Q % 4) — done once by wave 0
    if (gw == 0) {
        for (int q = nquad * 4; q < Q; ++q) {
            float mu = mus[q], sg = sigmas[q];
            float r = fmaf(mu, mu, sg * sg);
#pragma unroll
            for (int k = 0; k < 4; ++k)
                acc[k][0] = fminf(acc[k][0], fmaf(m2[k], mu, fmaf(s2[k], sg, r)));
        }
    }

    float a[4];
#pragma unroll
    for (int k = 0; k < 4; ++k)
        a[k] = fminf(fminf(acc[k][0], acc[k][1]), fminf(acc[k][2], acc[k][3]));

    __shared__ float red[4][NB];
#pragma unroll
    for (int k = 0; k < 4; ++k) red[wid][lane + 64 * k] = a[k];
    __syncthreads();

    const int b = threadIdx.x;
    float v = fminf(fminf(red[0][b], red[1][b]), fminf(red[2][b], red[3][b]));
    // un-shift: d2 = d' + (mean_b^2 + std_b^2); clamp >=0 for bitwise atomicMin
    const float mb = stats[b], sb = stats[NB + b];
    v = fmaxf(v + fmaf(mb, mb, sb * sb), 0.f);
    atomicMin(&minbits[b], __float_as_uint(v));
}

// ---------------------------------------------------------------------------
// Kernel 3: T = exp(-T_k * sqrt(min_sq))
// ---------------------------------------------------------------------------
__global__ void final_kernel(const unsigned int* __restrict__ minbits,
                             float* __restrict__ out) {
    const int b = threadIdx.x;
    float d2 = __uint_as_float(minbits[b]);
    out[b] = expf(-T_K * sqrtf(d2));
}

extern "C" void kernel_launch(void* const* d_in, const int* in_sizes, int n_in,
                              void* d_out, int out_size, void* d_ws, size_t ws_size,
                              hipStream_t stream) {
    const float* features = (const float*)d_in[0];
    // d_in[1]=labels, d_in[2]=pred, d_in[3]=confidence -- unused by reference
    const float* queue_mus    = (const float*)d_in[4];
    const float* queue_sigmas = (const float*)d_in[5];
    const int Q = in_sizes[4];

    float*        stats   = (float*)d_ws;                       // [0..255] means, [256..511] stds
    unsigned int* minbits = (unsigned int*)((float*)d_ws + 2 * NB);

    stats_kernel<<<NB, 256, 0, stream>>>(features, stats, minbits);
    scan_kernel<<<SCAN_BLOCKS, 256, 0, stream>>>(queue_mus, queue_sigmas, stats, minbits, Q);
    final_kernel<<<1, NB, 0, stream>>>(minbits, (float*)d_out);
}